// Round 19
// baseline (120.742 us; speedup 1.0000x reference)
//
#include <hip/hip_runtime.h>

// ---------- types ----------
typedef float f32x4  __attribute__((ext_vector_type(4)));
typedef float f32x16 __attribute__((ext_vector_type(16)));
typedef short bh8    __attribute__((ext_vector_type(8)));   // 8 bf16 in 4 VGPRs
typedef unsigned int u32;

#define MFMA16(a, b, c) __builtin_amdgcn_mfma_f32_16x16x32_bf16(a, b, c, 0, 0, 0)
#define MFMA32(a, b, c) __builtin_amdgcn_mfma_f32_32x32x16_bf16(a, b, c, 0, 0, 0)

// dims
#define BB 2
#define SS 2048
#define DD 1024
#define HH 16
#define HDIM 64
#define TT (BB * SS)   // 4096

#define QSCALE 0.18033688011f   // log2(e)/8 : folds 1/sqrt(64) + exp->exp2

__device__ __forceinline__ unsigned short f2bf(float f) {
  unsigned u = __float_as_uint(f);
  u += 0x7fffu + ((u >> 16) & 1u);   // RNE
  return (unsigned short)(u >> 16);
}
__device__ __forceinline__ u32 cvtpk(float lo, float hi) {
  u32 r;
  asm("v_cvt_pk_bf16_f32 %0, %1, %2" : "=v"(r) : "v"(lo), "v"(hi));
  return r;
}
// gfx950 ISA: v_permlane32_swap_b32 vdst, vsrc: a[32:63] <-> b[0:31].
#define PLSWAP(a, b) \
  asm("v_permlane32_swap_b32 %0, %1" : "+v"(a), "+v"(b))

// async global->LDS, 16B per lane (wave-uniform LDS base, lane l -> base+16l)
__device__ __forceinline__ void gload_lds16(const void* gsrc, const void* ldst) {
  __builtin_amdgcn_global_load_lds(
      (const __attribute__((address_space(1))) unsigned int*)(unsigned long long)gsrc,
      (__attribute__((address_space(3))) unsigned int*)(unsigned int)(unsigned long long)ldst,
      16, 0, 0);
}

// ---------- fp32 -> bf16 convert: x + all 4 weights in ONE launch ----------
__global__ void cvt_all(const float* __restrict__ x,
                        const float* __restrict__ w0, const float* __restrict__ w1,
                        const float* __restrict__ w2, const float* __restrict__ w3,
                        unsigned short* __restrict__ xb,
                        unsigned short* __restrict__ wb) {
  const int b = blockIdx.x;
  const float* src;
  unsigned short* dst;
  int i;
  if (b < 2048) {
    src = x; dst = xb;
    i = b * 256 + threadIdx.x;
  } else {
    const int z = (b - 2048) >> 9;             // 0..3
    src = (z == 0) ? w0 : (z == 1) ? w1 : (z == 2) ? w2 : w3;
    dst = wb + (size_t)z * 1048576;
    i = ((b - 2048) & 511) * 256 + threadIdx.x;
  }
  const float4* s = (const float4*)src;
  float4 a = s[i * 2 + 0];
  float4 c = s[i * 2 + 1];
  bh8 v;
  v[0] = (short)f2bf(a.x); v[1] = (short)f2bf(a.y);
  v[2] = (short)f2bf(a.z); v[3] = (short)f2bf(a.w);
  v[4] = (short)f2bf(c.x); v[5] = (short)f2bf(c.y);
  v[6] = (short)f2bf(c.z); v[7] = (short)f2bf(c.w);
  *(bh8*)(dst + (size_t)i * 8) = v;
}

// ---------- GEMM, T3 one-barrier pipeline; vectorized epilogues ----------
// EPI=0: QK (N=2048). TRANSPOSED MFMA(b,a): thread holds 4 consecutive n(hd)
//        -> one uint2 (4xbf16) store per fragment. Q pre-scaled by QSCALE.
// EPI=1: V (N=1024). Original MFMA(a,b): thread holds 4 consecutive m(s),
//        contiguous in V^T[hd][s] -> uint2 stores.
// EPI=2: out-proj (N=1024). Transposed -> float4 stores.
// Store count per thread: 64 scalar -> 16 vector (store-issue was ~20us).
template <int EPI>
__global__ __launch_bounds__(256) void gemm128(
    const unsigned short* __restrict__ A,
    const unsigned short* __restrict__ Bw,
    const float* __restrict__ b0, const float* __restrict__ b1,
    unsigned short* __restrict__ O0w, unsigned short* __restrict__ O1w,
    float* __restrict__ outf) {
  __shared__ __attribute__((aligned(16))) unsigned short As[2][128 * 32];
  __shared__ __attribute__((aligned(16))) unsigned short Bs[2][128 * 32];

  const int tid = threadIdx.x, lane = tid & 63, wid = tid >> 6;
  const int c = lane & 15, g = lane >> 4;
  const int wr = wid >> 1, wc = wid & 1;
  const int m0 = blockIdx.x * 128, n0 = blockIdx.y * 128;

  const unsigned short* Ab = A + (size_t)(m0 + (lane >> 2)) * DD + (lane & 3) * 8;
  const unsigned short* Bb = Bw + (size_t)(n0 + (lane >> 2)) * DD + (lane & 3) * 8;
  const int rowb0 = wid * 32, rowb1 = wid * 32 + 16;   // wave-uniform rows

  f32x4 acc[4][4];
#pragma unroll
  for (int mi = 0; mi < 4; ++mi)
#pragma unroll
    for (int ni = 0; ni < 4; ++ni) acc[mi][ni] = (f32x4){0.f, 0.f, 0.f, 0.f};

  // prologue: stage tile 0 into buf 0
  gload_lds16(Ab + (size_t)rowb0 * DD, &As[0][rowb0 * 32]);
  gload_lds16(Ab + (size_t)rowb1 * DD, &As[0][rowb1 * 32]);
  gload_lds16(Bb + (size_t)rowb0 * DD, &Bs[0][rowb0 * 32]);
  gload_lds16(Bb + (size_t)rowb1 * DD, &Bs[0][rowb1 * 32]);
  __syncthreads();   // vmcnt(0) drain: tile 0 visible

  const int NT = DD / 32;   // 32 K-steps
  for (int t = 0; t < NT; ++t) {
    const int cur = t & 1;
    if (t + 1 < NT) {
      const int k1 = (t + 1) * 32;
      gload_lds16(Ab + (size_t)rowb0 * DD + k1, &As[cur ^ 1][rowb0 * 32]);
      gload_lds16(Ab + (size_t)rowb1 * DD + k1, &As[cur ^ 1][rowb1 * 32]);
      gload_lds16(Bb + (size_t)rowb0 * DD + k1, &Bs[cur ^ 1][rowb0 * 32]);
      gload_lds16(Bb + (size_t)rowb1 * DD + k1, &Bs[cur ^ 1][rowb1 * 32]);
    }

    bh8 a[4], b[4];
#pragma unroll
    for (int mi = 0; mi < 4; ++mi)
      a[mi] = *(const bh8*)&As[cur][(wr * 64 + mi * 16 + c) * 32 + g * 8];
#pragma unroll
    for (int ni = 0; ni < 4; ++ni)
      b[ni] = *(const bh8*)&Bs[cur][(wc * 64 + ni * 16 + c) * 32 + g * 8];
    __builtin_amdgcn_s_setprio(1);
#pragma unroll
    for (int mi = 0; mi < 4; ++mi)
#pragma unroll
      for (int ni = 0; ni < 4; ++ni) {
        if (EPI == 1)
          acc[mi][ni] = MFMA16(a[mi], b[ni], acc[mi][ni]);   // rows=m, cols=n
        else
          acc[mi][ni] = MFMA16(b[ni], a[mi], acc[mi][ni]);   // rows=n, cols=m
      }
    __builtin_amdgcn_s_setprio(0);

    __syncthreads();   // retires reads of cur AND publishes tile t+1
  }

  if (EPI == 0) {
    // transposed: col c = m (s-dim), rows g*4+j = n (z,h,hd)
#pragma unroll
    for (int ni = 0; ni < 4; ++ni) {
      const int nb = n0 + wc * 64 + ni * 16 + g * 4;   // 4 consecutive n
      const int z = nb >> 10;                          // 0=Q 1=K (block-uniform)
      const int oo = nb & 1023;
      const int h = oo >> 6, hd = oo & 63;
      const float* bias = z ? b1 : b0;
      const float sc = z ? 1.0f : QSCALE;
      const float bs0 = bias[oo], bs1 = bias[oo + 1];
      const float bs2 = bias[oo + 2], bs3 = bias[oo + 3];
      unsigned short* Ow = z ? O1w : O0w;
#pragma unroll
      for (int mi = 0; mi < 4; ++mi) {
        const int m = m0 + wr * 64 + mi * 16 + c;
        const int bb = m >> 11, s = m & (SS - 1);
        uint2 v;
        v.x = cvtpk((acc[mi][ni][0] + bs0) * sc, (acc[mi][ni][1] + bs1) * sc);
        v.y = cvtpk((acc[mi][ni][2] + bs2) * sc, (acc[mi][ni][3] + bs3) * sc);
        *(uint2*)(Ow + (((size_t)(bb * HH + h) * SS + s) << 6) + hd) = v;
      }
    }
  } else if (EPI == 1) {
    // original: col c = n (h,hd), rows g*4+j = m (4 consecutive s)
#pragma unroll
    for (int ni = 0; ni < 4; ++ni) {
      const int n = n0 + wc * 64 + ni * 16 + c;
      const int h = n >> 6, hd = n & 63;
      const float bias = b0[n];
#pragma unroll
      for (int mi = 0; mi < 4; ++mi) {
        const int mb = m0 + wr * 64 + mi * 16 + g * 4;
        const int bb = mb >> 11, s = mb & (SS - 1);
        uint2 v;
        v.x = cvtpk(acc[mi][ni][0] + bias, acc[mi][ni][1] + bias);
        v.y = cvtpk(acc[mi][ni][2] + bias, acc[mi][ni][3] + bias);
        *(uint2*)(O0w + (((size_t)(bb * HH + h) * HDIM + hd) << 11) + s) = v;
      }
    }
  } else {
    // transposed fp32: thread holds 4 consecutive n -> float4
#pragma unroll
    for (int ni = 0; ni < 4; ++ni) {
      const int nb = n0 + wc * 64 + ni * 16 + g * 4;
      const float bs0 = b0[nb], bs1 = b0[nb + 1];
      const float bs2 = b0[nb + 2], bs3 = b0[nb + 3];
#pragma unroll
      for (int mi = 0; mi < 4; ++mi) {
        const int m = m0 + wr * 64 + mi * 16 + c;
        float4 v = {acc[mi][ni][0] + bs0, acc[mi][ni][1] + bs1,
                    acc[mi][ni][2] + bs2, acc[mi][ni][3] + bs3};
        *(float4*)(outf + (size_t)m * DD + nb) = v;
      }
    }
  }
}

// ---------- flash attention v10 (R18 frozen): padded [64][72] LDS ----------
__global__ __launch_bounds__(256, 3) void attn8(
    const unsigned short* __restrict__ Qw, const unsigned short* __restrict__ Kw,
    const unsigned short* __restrict__ Vtw, unsigned short* __restrict__ attnw) {
  __shared__ __attribute__((aligned(16))) unsigned short KT[2][64][72];
  __shared__ __attribute__((aligned(16))) unsigned short VT[2][64][72];

  const int f = blockIdx.x;
  const int work = (f & 7) * 64 + (f >> 3);   // bijective: 512 = 8*64
  const int bx = work & 15;                   // q-block (S/128)
  const int bh = work >> 4;                   // 0..31
  const int by = bh & 15, bz = bh >> 4;

  const int tid = threadIdx.x;
  const int lane = tid & 63, wid = tid >> 6;
  const int q = lane & 31, hi = lane >> 5;
  const unsigned short* Qb = Qw + (size_t)bh * SS * HDIM;
  const unsigned short* Kb = Kw + (size_t)bh * SS * HDIM;
  const unsigned short* Vb = Vtw + (size_t)bh * HDIM * SS;
  const int q0 = bx * 128 + wid * 32;

  bh8 qf[4];
#pragma unroll
  for (int ks = 0; ks < 4; ++ks)
    qf[ks] = *(const bh8*)(Qb + (size_t)(q0 + q) * HDIM + ks * 16 + hi * 8);

  f32x16 O0, O1;
#pragma unroll
  for (int r = 0; r < 16; ++r) { O0[r] = 0.f; O1[r] = 0.f; }
  float la[4] = {0.f, 0.f, 0.f, 0.f};

  const int srow = tid >> 2;
  const int scol = (tid & 3) * 16;
  const unsigned short* Ksrc = Kb + (size_t)srow * HDIM + scol;
  const unsigned short* Vsrc = Vb + (size_t)srow * SS + scol;

  bh8 kr0 = *(const bh8*)(Ksrc + 0), kr1 = *(const bh8*)(Ksrc + 8);
  bh8 vr0 = *(const bh8*)(Vsrc + 0), vr1 = *(const bh8*)(Vsrc + 8);
  *(bh8*)&KT[0][srow][scol] = kr0; *(bh8*)&KT[0][srow][scol + 8] = kr1;
  *(bh8*)&VT[0][srow][scol] = vr0; *(bh8*)&VT[0][srow][scol + 8] = vr1;
  kr0 = *(const bh8*)(Ksrc + 64 * HDIM); kr1 = *(const bh8*)(Ksrc + 64 * HDIM + 8);
  vr0 = *(const bh8*)(Vsrc + 64);        vr1 = *(const bh8*)(Vsrc + 64 + 8);

  const int NT = SS / 64;   // 32 tiles, full sequence
  for (int kt = 0; kt < NT; ++kt) {
    const int cur = kt & 1;
    __syncthreads();
    if (kt + 1 < NT) {
      *(bh8*)&KT[cur ^ 1][srow][scol] = kr0;
      *(bh8*)&KT[cur ^ 1][srow][scol + 8] = kr1;
      *(bh8*)&VT[cur ^ 1][srow][scol] = vr0;
      *(bh8*)&VT[cur ^ 1][srow][scol + 8] = vr1;
      if (kt + 2 < NT) {
        const size_t ko = (size_t)(kt + 2) * 64 * HDIM, vo = (size_t)(kt + 2) * 64;
        kr0 = *(const bh8*)(Ksrc + ko); kr1 = *(const bh8*)(Ksrc + ko + 8);
        vr0 = *(const bh8*)(Vsrc + vo); vr1 = *(const bh8*)(Vsrc + vo + 8);
      }
    }

#pragma unroll
    for (int kvt = 0; kvt < 2; ++kvt) {
      bh8 kf[4];
#pragma unroll
      for (int ks = 0; ks < 4; ++ks)
        kf[ks] = *(const bh8*)&KT[cur][kvt * 32 + q][ks * 16 + hi * 8];
      f32x16 a;
#pragma unroll
      for (int r = 0; r < 16; ++r) a[r] = 0.f;
      __builtin_amdgcn_s_setprio(1);
#pragma unroll
      for (int ks = 0; ks < 4; ++ks) a = MFMA32(kf[ks], qf[ks], a);
      __builtin_amdgcn_s_setprio(0);

      bh8 vf00 = *(const bh8*)&VT[cur][q][kvt * 32 + hi * 8];
      bh8 vf01 = *(const bh8*)&VT[cur][32 + q][kvt * 32 + hi * 8];
      bh8 vf10 = *(const bh8*)&VT[cur][q][kvt * 32 + 16 + hi * 8];
      bh8 vf11 = *(const bh8*)&VT[cur][32 + q][kvt * 32 + 16 + hi * 8];

      u32 w[8];
#pragma unroll
      for (int i = 0; i < 8; ++i) {
        float p0 = __builtin_amdgcn_exp2f(a[2 * i]);
        float p1 = __builtin_amdgcn_exp2f(a[2 * i + 1]);
        la[i & 3] += p0 + p1;
        w[i] = cvtpk(p0, p1);
      }
      PLSWAP(w[0], w[2]); PLSWAP(w[1], w[3]);
      PLSWAP(w[4], w[6]); PLSWAP(w[5], w[7]);

      union { u32 uw[4]; bh8 h; } pa0, pa1;
#pragma unroll
      for (int j = 0; j < 4; ++j) { pa0.uw[j] = w[j]; pa1.uw[j] = w[4 + j]; }
      __builtin_amdgcn_s_setprio(1);
      O0 = MFMA32(vf00, pa0.h, O0);
      O1 = MFMA32(vf01, pa0.h, O1);
      O0 = MFMA32(vf10, pa1.h, O0);
      O1 = MFMA32(vf11, pa1.h, O1);
      __builtin_amdgcn_s_setprio(0);
    }
  }

  // ---- epilogue: l row-total (cross-half once), normalized bf16 output ----
  float l = (la[0] + la[1]) + (la[2] + la[3]);
  {
    float xa = l, xb = l;
    asm("" : "+v"(xb));
    PLSWAP(xa, xb);
    l = xa + xb;
  }
  const float inv = 1.0f / l;
  unsigned short* orow =
      attnw + (size_t)(bz * SS + q0 + q) * DD + by * HDIM;
#pragma unroll
  for (int rq = 0; rq < 4; ++rq) {
    const int db0 = 8 * rq + 4 * hi;
    uint2 v0, v1;
    v0.x = cvtpk(O0[4 * rq + 0] * inv, O0[4 * rq + 1] * inv);
    v0.y = cvtpk(O0[4 * rq + 2] * inv, O0[4 * rq + 3] * inv);
    v1.x = cvtpk(O1[4 * rq + 0] * inv, O1[4 * rq + 1] * inv);
    v1.y = cvtpk(O1[4 * rq + 2] * inv, O1[4 * rq + 3] * inv);
    *(uint2*)(orow + db0) = v0;
    *(uint2*)(orow + 32 + db0) = v1;
  }
}

// ---------- launch ----------
extern "C" void kernel_launch(void* const* d_in, const int* in_sizes, int n_in,
                              void* d_out, int out_size, void* d_ws,
                              size_t ws_size, hipStream_t stream) {
  const float* x  = (const float*)d_in[0];
  const float* Wq = (const float*)d_in[1];
  const float* bq = (const float*)d_in[2];
  const float* Wk = (const float*)d_in[3];
  const float* bk = (const float*)d_in[4];
  const float* Wv = (const float*)d_in[5];
  const float* bv = (const float*)d_in[6];
  const float* Wo = (const float*)d_in[7];
  const float* bo = (const float*)d_in[8];
  float* out = (float*)d_out;

  unsigned short* ws = (unsigned short*)d_ws;
  unsigned short* xb    = ws;                    // 4M  [T,D]
  unsigned short* Wqb   = ws + 4194304;          // 1M x4 (Wq,Wk,Wv,Wo contiguous)
  unsigned short* Qw    = ws + 8388608;          // 4M  [bh][s][hd] (pre-scaled)
  unsigned short* Kw    = ws + 12582912;         // 4M  [bh][s][hd]
  unsigned short* Vtw   = ws + 16777216;         // 4M  [bh][hd][s]
  unsigned short* attnw = ws + 20971520;         // 4M  [T,D]

  cvt_all<<<dim3(4096), 256, 0, stream>>>(x, Wq, Wk, Wv, Wo, xb, Wqb);

  // QK projection: N=2048 (Wq,Wk contiguous), transposed epilogue
  gemm128<0><<<dim3(TT / 128, 2048 / 128), 256, 0, stream>>>(
      xb, Wqb, bq, bk, Qw, Kw, nullptr);
  // V projection: N=1024, original orientation (s-contiguous V^T stores)
  gemm128<1><<<dim3(TT / 128, 1024 / 128), 256, 0, stream>>>(
      xb, Wqb + 2 * 1048576, bv, nullptr, Vtw, nullptr, nullptr);

  attn8<<<dim3(512), 256, 0, stream>>>(Qw, Kw, Vtw, attnw);

  // out projection: N=1024, transposed epilogue (float4 stores)
  gemm128<2><<<dim3(TT / 128, 1024 / 128), 256, 0, stream>>>(
      attnw, Wqb + 3 * 1048576, bo, nullptr, nullptr, nullptr, out);
}

// Round 20
// 102.414 us; speedup vs baseline: 1.1790x; 1.1790x over previous
//
#include <hip/hip_runtime.h>

// ---------- types ----------
typedef float f32x4  __attribute__((ext_vector_type(4)));
typedef float f32x16 __attribute__((ext_vector_type(16)));
typedef short bh8    __attribute__((ext_vector_type(8)));   // 8 bf16 in 4 VGPRs
typedef unsigned int u32;

#define MFMA16(a, b, c) __builtin_amdgcn_mfma_f32_16x16x32_bf16(a, b, c, 0, 0, 0)
#define MFMA32(a, b, c) __builtin_amdgcn_mfma_f32_32x32x16_bf16(a, b, c, 0, 0, 0)

// dims
#define BB 2
#define SS 2048
#define DD 1024
#define HH 16
#define HDIM 64
#define TT (BB * SS)   // 4096

#define QSCALE 0.18033688011f   // log2(e)/8 : folds 1/sqrt(64) + exp->exp2

__device__ __forceinline__ unsigned short f2bf(float f) {
  unsigned u = __float_as_uint(f);
  u += 0x7fffu + ((u >> 16) & 1u);   // RNE
  return (unsigned short)(u >> 16);
}
__device__ __forceinline__ u32 cvtpk(float lo, float hi) {
  u32 r;
  asm("v_cvt_pk_bf16_f32 %0, %1, %2" : "=v"(r) : "v"(lo), "v"(hi));
  return r;
}
// gfx950 ISA: v_permlane32_swap_b32 vdst, vsrc: a[32:63] <-> b[0:31].
#define PLSWAP(a, b) \
  asm("v_permlane32_swap_b32 %0, %1" : "+v"(a), "+v"(b))

// async global->LDS, 16B per lane (wave-uniform LDS base, lane l -> base+16l)
__device__ __forceinline__ void gload_lds16(const void* gsrc, const void* ldst) {
  __builtin_amdgcn_global_load_lds(
      (const __attribute__((address_space(1))) unsigned int*)(unsigned long long)gsrc,
      (__attribute__((address_space(3))) unsigned int*)(unsigned int)(unsigned long long)ldst,
      16, 0, 0);
}

// ---------- fp32 -> bf16 convert: x + all 4 weights in ONE launch ----------
__global__ void cvt_all(const float* __restrict__ x,
                        const float* __restrict__ w0, const float* __restrict__ w1,
                        const float* __restrict__ w2, const float* __restrict__ w3,
                        unsigned short* __restrict__ xb,
                        unsigned short* __restrict__ wb) {
  const int b = blockIdx.x;
  const float* src;
  unsigned short* dst;
  int i;
  if (b < 2048) {
    src = x; dst = xb;
    i = b * 256 + threadIdx.x;
  } else {
    const int z = (b - 2048) >> 9;             // 0..3
    src = (z == 0) ? w0 : (z == 1) ? w1 : (z == 2) ? w2 : w3;
    dst = wb + (size_t)z * 1048576;
    i = ((b - 2048) & 511) * 256 + threadIdx.x;
  }
  const float4* s = (const float4*)src;
  float4 a = s[i * 2 + 0];
  float4 c = s[i * 2 + 1];
  bh8 v;
  v[0] = (short)f2bf(a.x); v[1] = (short)f2bf(a.y);
  v[2] = (short)f2bf(a.z); v[3] = (short)f2bf(a.w);
  v[4] = (short)f2bf(c.x); v[5] = (short)f2bf(c.y);
  v[6] = (short)f2bf(c.z); v[7] = (short)f2bf(c.w);
  *(bh8*)(dst + (size_t)i * 8) = v;
}

// ---------- GEMM, T3 one-barrier double-buffered pipeline ----------
// R18 structure (fused QKV epilogue, lane-contiguous stores) with:
//  (1) __launch_bounds__(256,4): ask for <=128 unified regs (was ~132)
//      -> 4 blocks/CU. GEMM path is reg-config-robust (gload_lds+barriers).
//  (2) V branch (z==2): 4 consecutive-s scalar stores packed into 2 uint2
//      (same per-lane addresses -> coalescing unchanged; RNE identical).
template <int EPI>
__global__ __launch_bounds__(256, 4) void gemm128(
    const unsigned short* __restrict__ A,
    const unsigned short* __restrict__ Bw,
    const float* __restrict__ b0, const float* __restrict__ b1,
    const float* __restrict__ b2,
    unsigned short* __restrict__ Qw, unsigned short* __restrict__ Kw,
    unsigned short* __restrict__ Vtw, float* __restrict__ outf) {
  __shared__ __attribute__((aligned(16))) unsigned short As[2][128 * 32];
  __shared__ __attribute__((aligned(16))) unsigned short Bs[2][128 * 32];

  const int tid = threadIdx.x, lane = tid & 63, wid = tid >> 6;
  const int c = lane & 15, g = lane >> 4;
  const int wr = wid >> 1, wc = wid & 1;
  const int m0 = blockIdx.x * 128, n0 = blockIdx.y * 128;

  const unsigned short* Ab = A + (size_t)(m0 + (lane >> 2)) * DD + (lane & 3) * 8;
  const unsigned short* Bb = Bw + (size_t)(n0 + (lane >> 2)) * DD + (lane & 3) * 8;
  const int rowb0 = wid * 32, rowb1 = wid * 32 + 16;   // wave-uniform rows

  f32x4 acc[4][4];
#pragma unroll
  for (int mi = 0; mi < 4; ++mi)
#pragma unroll
    for (int ni = 0; ni < 4; ++ni) acc[mi][ni] = (f32x4){0.f, 0.f, 0.f, 0.f};

  // prologue: stage tile 0 into buf 0
  gload_lds16(Ab + (size_t)rowb0 * DD, &As[0][rowb0 * 32]);
  gload_lds16(Ab + (size_t)rowb1 * DD, &As[0][rowb1 * 32]);
  gload_lds16(Bb + (size_t)rowb0 * DD, &Bs[0][rowb0 * 32]);
  gload_lds16(Bb + (size_t)rowb1 * DD, &Bs[0][rowb1 * 32]);
  __syncthreads();   // vmcnt(0) drain: tile 0 visible

  const int NT = DD / 32;   // 32 K-steps
  for (int t = 0; t < NT; ++t) {
    const int cur = t & 1;
    if (t + 1 < NT) {
      const int k1 = (t + 1) * 32;
      gload_lds16(Ab + (size_t)rowb0 * DD + k1, &As[cur ^ 1][rowb0 * 32]);
      gload_lds16(Ab + (size_t)rowb1 * DD + k1, &As[cur ^ 1][rowb1 * 32]);
      gload_lds16(Bb + (size_t)rowb0 * DD + k1, &Bs[cur ^ 1][rowb0 * 32]);
      gload_lds16(Bb + (size_t)rowb1 * DD + k1, &Bs[cur ^ 1][rowb1 * 32]);
    }

    bh8 a[4], b[4];
#pragma unroll
    for (int mi = 0; mi < 4; ++mi)
      a[mi] = *(const bh8*)&As[cur][(wr * 64 + mi * 16 + c) * 32 + g * 8];
#pragma unroll
    for (int ni = 0; ni < 4; ++ni)
      b[ni] = *(const bh8*)&Bs[cur][(wc * 64 + ni * 16 + c) * 32 + g * 8];
    __builtin_amdgcn_s_setprio(1);
#pragma unroll
    for (int mi = 0; mi < 4; ++mi)
#pragma unroll
      for (int ni = 0; ni < 4; ++ni)
        acc[mi][ni] = MFMA16(a[mi], b[ni], acc[mi][ni]);
    __builtin_amdgcn_s_setprio(0);

    __syncthreads();   // retires reads of cur AND publishes tile t+1
  }

  if (EPI == 0) {
#pragma unroll
    for (int ni = 0; ni < 4; ++ni) {
      const int n = n0 + wc * 64 + ni * 16 + c;
      const int z = n >> 10, oo = n & 1023;
      const float bias = (z == 0 ? b0 : (z == 1 ? b1 : b2))[oo];
      const int h = oo >> 6, hd = oo & 63;
      if (z == 2) {
        // V: 4 consecutive s per (mi) -> 2 uint2 stores (same addresses)
#pragma unroll
        for (int mi = 0; mi < 4; ++mi) {
          const int mb = m0 + wr * 64 + mi * 16 + g * 4;
          const int bb = mb >> 11, s = mb & (SS - 1);
          uint2 v;
          v.x = cvtpk(acc[mi][ni][0] + bias, acc[mi][ni][1] + bias);
          v.y = cvtpk(acc[mi][ni][2] + bias, acc[mi][ni][3] + bias);
          *(uint2*)(Vtw + (((size_t)(bb * HH + h) * HDIM + hd) << 11) + s) = v;
        }
      } else {
        unsigned short* O = (z == 0) ? Qw : Kw;
        const float sc = (z == 0) ? QSCALE : 1.0f;
#pragma unroll
        for (int mi = 0; mi < 4; ++mi)
#pragma unroll
          for (int j = 0; j < 4; ++j) {
            const int m = m0 + wr * 64 + mi * 16 + g * 4 + j;
            const int bb = m >> 11, s = m & (SS - 1);
            O[(((size_t)(bb * HH + h) * SS + s) << 6) + hd] =
                f2bf((acc[mi][ni][j] + bias) * sc);
          }
      }
    }
  } else {
#pragma unroll
    for (int ni = 0; ni < 4; ++ni) {
      const int n = n0 + wc * 64 + ni * 16 + c;
      const float bias = b0[n];
#pragma unroll
      for (int mi = 0; mi < 4; ++mi)
#pragma unroll
        for (int j = 0; j < 4; ++j) {
          const int m = m0 + wr * 64 + mi * 16 + g * 4 + j;
          outf[(size_t)m * DD + n] = acc[mi][ni][j] + bias;
        }
    }
  }
}

// ---------- flash attention v10 (R18 frozen): padded [64][72] LDS ----------
__global__ __launch_bounds__(256, 3) void attn8(
    const unsigned short* __restrict__ Qw, const unsigned short* __restrict__ Kw,
    const unsigned short* __restrict__ Vtw, unsigned short* __restrict__ attnw) {
  __shared__ __attribute__((aligned(16))) unsigned short KT[2][64][72];
  __shared__ __attribute__((aligned(16))) unsigned short VT[2][64][72];

  const int f = blockIdx.x;
  const int work = (f & 7) * 64 + (f >> 3);   // bijective: 512 = 8*64
  const int bx = work & 15;                   // q-block (S/128)
  const int bh = work >> 4;                   // 0..31
  const int by = bh & 15, bz = bh >> 4;

  const int tid = threadIdx.x;
  const int lane = tid & 63, wid = tid >> 6;
  const int q = lane & 31, hi = lane >> 5;
  const unsigned short* Qb = Qw + (size_t)bh * SS * HDIM;
  const unsigned short* Kb = Kw + (size_t)bh * SS * HDIM;
  const unsigned short* Vb = Vtw + (size_t)bh * HDIM * SS;
  const int q0 = bx * 128 + wid * 32;

  bh8 qf[4];
#pragma unroll
  for (int ks = 0; ks < 4; ++ks)
    qf[ks] = *(const bh8*)(Qb + (size_t)(q0 + q) * HDIM + ks * 16 + hi * 8);

  f32x16 O0, O1;
#pragma unroll
  for (int r = 0; r < 16; ++r) { O0[r] = 0.f; O1[r] = 0.f; }
  float la[4] = {0.f, 0.f, 0.f, 0.f};

  const int srow = tid >> 2;
  const int scol = (tid & 3) * 16;
  const unsigned short* Ksrc = Kb + (size_t)srow * HDIM + scol;
  const unsigned short* Vsrc = Vb + (size_t)srow * SS + scol;

  bh8 kr0 = *(const bh8*)(Ksrc + 0), kr1 = *(const bh8*)(Ksrc + 8);
  bh8 vr0 = *(const bh8*)(Vsrc + 0), vr1 = *(const bh8*)(Vsrc + 8);
  *(bh8*)&KT[0][srow][scol] = kr0; *(bh8*)&KT[0][srow][scol + 8] = kr1;
  *(bh8*)&VT[0][srow][scol] = vr0; *(bh8*)&VT[0][srow][scol + 8] = vr1;
  kr0 = *(const bh8*)(Ksrc + 64 * HDIM); kr1 = *(const bh8*)(Ksrc + 64 * HDIM + 8);
  vr0 = *(const bh8*)(Vsrc + 64);        vr1 = *(const bh8*)(Vsrc + 64 + 8);

  const int NT = SS / 64;   // 32 tiles, full sequence
  for (int kt = 0; kt < NT; ++kt) {
    const int cur = kt & 1;
    __syncthreads();
    if (kt + 1 < NT) {
      *(bh8*)&KT[cur ^ 1][srow][scol] = kr0;
      *(bh8*)&KT[cur ^ 1][srow][scol + 8] = kr1;
      *(bh8*)&VT[cur ^ 1][srow][scol] = vr0;
      *(bh8*)&VT[cur ^ 1][srow][scol + 8] = vr1;
      if (kt + 2 < NT) {
        const size_t ko = (size_t)(kt + 2) * 64 * HDIM, vo = (size_t)(kt + 2) * 64;
        kr0 = *(const bh8*)(Ksrc + ko); kr1 = *(const bh8*)(Ksrc + ko + 8);
        vr0 = *(const bh8*)(Vsrc + vo); vr1 = *(const bh8*)(Vsrc + vo + 8);
      }
    }

#pragma unroll
    for (int kvt = 0; kvt < 2; ++kvt) {
      bh8 kf[4];
#pragma unroll
      for (int ks = 0; ks < 4; ++ks)
        kf[ks] = *(const bh8*)&KT[cur][kvt * 32 + q][ks * 16 + hi * 8];
      f32x16 a;
#pragma unroll
      for (int r = 0; r < 16; ++r) a[r] = 0.f;
      __builtin_amdgcn_s_setprio(1);
#pragma unroll
      for (int ks = 0; ks < 4; ++ks) a = MFMA32(kf[ks], qf[ks], a);
      __builtin_amdgcn_s_setprio(0);

      bh8 vf00 = *(const bh8*)&VT[cur][q][kvt * 32 + hi * 8];
      bh8 vf01 = *(const bh8*)&VT[cur][32 + q][kvt * 32 + hi * 8];
      bh8 vf10 = *(const bh8*)&VT[cur][q][kvt * 32 + 16 + hi * 8];
      bh8 vf11 = *(const bh8*)&VT[cur][32 + q][kvt * 32 + 16 + hi * 8];

      u32 w[8];
#pragma unroll
      for (int i = 0; i < 8; ++i) {
        float p0 = __builtin_amdgcn_exp2f(a[2 * i]);
        float p1 = __builtin_amdgcn_exp2f(a[2 * i + 1]);
        la[i & 3] += p0 + p1;
        w[i] = cvtpk(p0, p1);
      }
      PLSWAP(w[0], w[2]); PLSWAP(w[1], w[3]);
      PLSWAP(w[4], w[6]); PLSWAP(w[5], w[7]);

      union { u32 uw[4]; bh8 h; } pa0, pa1;
#pragma unroll
      for (int j = 0; j < 4; ++j) { pa0.uw[j] = w[j]; pa1.uw[j] = w[4 + j]; }
      __builtin_amdgcn_s_setprio(1);
      O0 = MFMA32(vf00, pa0.h, O0);
      O1 = MFMA32(vf01, pa0.h, O1);
      O0 = MFMA32(vf10, pa1.h, O0);
      O1 = MFMA32(vf11, pa1.h, O1);
      __builtin_amdgcn_s_setprio(0);
    }
  }

  // ---- epilogue: l row-total (cross-half once), normalized bf16 output ----
  float l = (la[0] + la[1]) + (la[2] + la[3]);
  {
    float xa = l, xb = l;
    asm("" : "+v"(xb));
    PLSWAP(xa, xb);
    l = xa + xb;
  }
  const float inv = 1.0f / l;
  unsigned short* orow =
      attnw + (size_t)(bz * SS + q0 + q) * DD + by * HDIM;
#pragma unroll
  for (int rq = 0; rq < 4; ++rq) {
    const int db0 = 8 * rq + 4 * hi;
    uint2 v0, v1;
    v0.x = cvtpk(O0[4 * rq + 0] * inv, O0[4 * rq + 1] * inv);
    v0.y = cvtpk(O0[4 * rq + 2] * inv, O0[4 * rq + 3] * inv);
    v1.x = cvtpk(O1[4 * rq + 0] * inv, O1[4 * rq + 1] * inv);
    v1.y = cvtpk(O1[4 * rq + 2] * inv, O1[4 * rq + 3] * inv);
    *(uint2*)(orow + db0) = v0;
    *(uint2*)(orow + 32 + db0) = v1;
  }
}

// ---------- launch ----------
extern "C" void kernel_launch(void* const* d_in, const int* in_sizes, int n_in,
                              void* d_out, int out_size, void* d_ws,
                              size_t ws_size, hipStream_t stream) {
  const float* x  = (const float*)d_in[0];
  const float* Wq = (const float*)d_in[1];
  const float* bq = (const float*)d_in[2];
  const float* Wk = (const float*)d_in[3];
  const float* bk = (const float*)d_in[4];
  const float* Wv = (const float*)d_in[5];
  const float* bv = (const float*)d_in[6];
  const float* Wo = (const float*)d_in[7];
  const float* bo = (const float*)d_in[8];
  float* out = (float*)d_out;

  unsigned short* ws = (unsigned short*)d_ws;
  unsigned short* xb    = ws;                    // 4M  [T,D]
  unsigned short* Wqb   = ws + 4194304;          // 1M x4 (Wq,Wk,Wv,Wo contiguous)
  unsigned short* Qw    = ws + 8388608;          // 4M  [bh][s][hd] (pre-scaled)
  unsigned short* Kw    = ws + 12582912;         // 4M  [bh][s][hd]
  unsigned short* Vtw   = ws + 16777216;         // 4M  [bh][hd][s]
  unsigned short* attnw = ws + 20971520;         // 4M  [T,D]

  cvt_all<<<dim3(4096), 256, 0, stream>>>(x, Wq, Wk, Wv, Wo, xb, Wqb);

  gemm128<0><<<dim3(TT / 128, 3072 / 128), 256, 0, stream>>>(
      xb, Wqb, bq, bk, bv, Qw, Kw, Vtw, nullptr);

  attn8<<<dim3(512), 256, 0, stream>>>(Qw, Kw, Vtw, attnw);

  gemm128<1><<<dim3(TT / 128, DD / 128), 256, 0, stream>>>(
      attnw, Wqb + 3 * 1048576, bo, nullptr, nullptr, nullptr, nullptr, nullptr, out);
}

// Round 21
// 101.615 us; speedup vs baseline: 1.1882x; 1.0079x over previous
//
#include <hip/hip_runtime.h>

// ---------- types ----------
typedef float f32x4  __attribute__((ext_vector_type(4)));
typedef float f32x16 __attribute__((ext_vector_type(16)));
typedef short bh8    __attribute__((ext_vector_type(8)));   // 8 bf16 in 4 VGPRs
typedef unsigned int u32;

#define MFMA16(a, b, c) __builtin_amdgcn_mfma_f32_16x16x32_bf16(a, b, c, 0, 0, 0)
#define MFMA32(a, b, c) __builtin_amdgcn_mfma_f32_32x32x16_bf16(a, b, c, 0, 0, 0)

// dims
#define BB 2
#define SS 2048
#define DD 1024
#define HH 16
#define HDIM 64
#define TT (BB * SS)   // 4096

#define QSCALE 0.18033688011f   // log2(e)/8 : folds 1/sqrt(64) + exp->exp2

__device__ __forceinline__ unsigned short f2bf(float f) {
  unsigned u = __float_as_uint(f);
  u += 0x7fffu + ((u >> 16) & 1u);   // RNE
  return (unsigned short)(u >> 16);
}
__device__ __forceinline__ u32 cvtpk(float lo, float hi) {
  u32 r;
  asm("v_cvt_pk_bf16_f32 %0, %1, %2" : "=v"(r) : "v"(lo), "v"(hi));
  return r;
}
// gfx950 ISA: v_permlane32_swap_b32 vdst, vsrc: a[32:63] <-> b[0:31].
#define PLSWAP(a, b) \
  asm("v_permlane32_swap_b32 %0, %1" : "+v"(a), "+v"(b))

// async global->LDS, 16B per lane (wave-uniform LDS base, lane l -> base+16l)
__device__ __forceinline__ void gload_lds16(const void* gsrc, const void* ldst) {
  __builtin_amdgcn_global_load_lds(
      (const __attribute__((address_space(1))) unsigned int*)(unsigned long long)gsrc,
      (__attribute__((address_space(3))) unsigned int*)(unsigned int)(unsigned long long)ldst,
      16, 0, 0);
}

// ---------- fp32 -> bf16 convert: x + all 4 weights in ONE launch ----------
__global__ void cvt_all(const float* __restrict__ x,
                        const float* __restrict__ w0, const float* __restrict__ w1,
                        const float* __restrict__ w2, const float* __restrict__ w3,
                        unsigned short* __restrict__ xb,
                        unsigned short* __restrict__ wb) {
  const int b = blockIdx.x;
  const float* src;
  unsigned short* dst;
  int i;
  if (b < 2048) {
    src = x; dst = xb;
    i = b * 256 + threadIdx.x;
  } else {
    const int z = (b - 2048) >> 9;             // 0..3
    src = (z == 0) ? w0 : (z == 1) ? w1 : (z == 2) ? w2 : w3;
    dst = wb + (size_t)z * 1048576;
    i = ((b - 2048) & 511) * 256 + threadIdx.x;
  }
  const float4* s = (const float4*)src;
  float4 a = s[i * 2 + 0];
  float4 c = s[i * 2 + 1];
  bh8 v;
  v[0] = (short)f2bf(a.x); v[1] = (short)f2bf(a.y);
  v[2] = (short)f2bf(a.z); v[3] = (short)f2bf(a.w);
  v[4] = (short)f2bf(c.x); v[5] = (short)f2bf(c.y);
  v[6] = (short)f2bf(c.z); v[7] = (short)f2bf(c.w);
  *(bh8*)(dst + (size_t)i * 8) = v;
}

// ---------- GEMM, T3 one-barrier double-buffered pipeline (R20 frozen) ----------
template <int EPI>
__global__ __launch_bounds__(256, 4) void gemm128(
    const unsigned short* __restrict__ A,
    const unsigned short* __restrict__ Bw,
    const float* __restrict__ b0, const float* __restrict__ b1,
    const float* __restrict__ b2,
    unsigned short* __restrict__ Qw, unsigned short* __restrict__ Kw,
    unsigned short* __restrict__ Vtw, float* __restrict__ outf) {
  __shared__ __attribute__((aligned(16))) unsigned short As[2][128 * 32];
  __shared__ __attribute__((aligned(16))) unsigned short Bs[2][128 * 32];

  const int tid = threadIdx.x, lane = tid & 63, wid = tid >> 6;
  const int c = lane & 15, g = lane >> 4;
  const int wr = wid >> 1, wc = wid & 1;
  const int m0 = blockIdx.x * 128, n0 = blockIdx.y * 128;

  const unsigned short* Ab = A + (size_t)(m0 + (lane >> 2)) * DD + (lane & 3) * 8;
  const unsigned short* Bb = Bw + (size_t)(n0 + (lane >> 2)) * DD + (lane & 3) * 8;
  const int rowb0 = wid * 32, rowb1 = wid * 32 + 16;   // wave-uniform rows

  f32x4 acc[4][4];
#pragma unroll
  for (int mi = 0; mi < 4; ++mi)
#pragma unroll
    for (int ni = 0; ni < 4; ++ni) acc[mi][ni] = (f32x4){0.f, 0.f, 0.f, 0.f};

  // prologue: stage tile 0 into buf 0
  gload_lds16(Ab + (size_t)rowb0 * DD, &As[0][rowb0 * 32]);
  gload_lds16(Ab + (size_t)rowb1 * DD, &As[0][rowb1 * 32]);
  gload_lds16(Bb + (size_t)rowb0 * DD, &Bs[0][rowb0 * 32]);
  gload_lds16(Bb + (size_t)rowb1 * DD, &Bs[0][rowb1 * 32]);
  __syncthreads();   // vmcnt(0) drain: tile 0 visible

  const int NT = DD / 32;   // 32 K-steps
  for (int t = 0; t < NT; ++t) {
    const int cur = t & 1;
    if (t + 1 < NT) {
      const int k1 = (t + 1) * 32;
      gload_lds16(Ab + (size_t)rowb0 * DD + k1, &As[cur ^ 1][rowb0 * 32]);
      gload_lds16(Ab + (size_t)rowb1 * DD + k1, &As[cur ^ 1][rowb1 * 32]);
      gload_lds16(Bb + (size_t)rowb0 * DD + k1, &Bs[cur ^ 1][rowb0 * 32]);
      gload_lds16(Bb + (size_t)rowb1 * DD + k1, &Bs[cur ^ 1][rowb1 * 32]);
    }

    bh8 a[4], b[4];
#pragma unroll
    for (int mi = 0; mi < 4; ++mi)
      a[mi] = *(const bh8*)&As[cur][(wr * 64 + mi * 16 + c) * 32 + g * 8];
#pragma unroll
    for (int ni = 0; ni < 4; ++ni)
      b[ni] = *(const bh8*)&Bs[cur][(wc * 64 + ni * 16 + c) * 32 + g * 8];
    __builtin_amdgcn_s_setprio(1);
#pragma unroll
    for (int mi = 0; mi < 4; ++mi)
#pragma unroll
      for (int ni = 0; ni < 4; ++ni)
        acc[mi][ni] = MFMA16(a[mi], b[ni], acc[mi][ni]);
    __builtin_amdgcn_s_setprio(0);

    __syncthreads();   // retires reads of cur AND publishes tile t+1
  }

  if (EPI == 0) {
#pragma unroll
    for (int ni = 0; ni < 4; ++ni) {
      const int n = n0 + wc * 64 + ni * 16 + c;
      const int z = n >> 10, oo = n & 1023;
      const float bias = (z == 0 ? b0 : (z == 1 ? b1 : b2))[oo];
      const int h = oo >> 6, hd = oo & 63;
      if (z == 2) {
        // V: 4 consecutive s per (mi) -> 2 uint2 stores (same addresses)
#pragma unroll
        for (int mi = 0; mi < 4; ++mi) {
          const int mb = m0 + wr * 64 + mi * 16 + g * 4;
          const int bb = mb >> 11, s = mb & (SS - 1);
          uint2 v;
          v.x = cvtpk(acc[mi][ni][0] + bias, acc[mi][ni][1] + bias);
          v.y = cvtpk(acc[mi][ni][2] + bias, acc[mi][ni][3] + bias);
          *(uint2*)(Vtw + (((size_t)(bb * HH + h) * HDIM + hd) << 11) + s) = v;
        }
      } else {
        unsigned short* O = (z == 0) ? Qw : Kw;
        const float sc = (z == 0) ? QSCALE : 1.0f;
#pragma unroll
        for (int mi = 0; mi < 4; ++mi)
#pragma unroll
          for (int j = 0; j < 4; ++j) {
            const int m = m0 + wr * 64 + mi * 16 + g * 4 + j;
            const int bb = m >> 11, s = m & (SS - 1);
            O[(((size_t)(bb * HH + h) * SS + s) << 6) + hd] =
                f2bf((acc[mi][ni][j] + bias) * sc);
          }
      }
    }
  } else {
#pragma unroll
    for (int ni = 0; ni < 4; ++ni) {
      const int n = n0 + wc * 64 + ni * 16 + c;
      const float bias = b0[n];
#pragma unroll
      for (int mi = 0; mi < 4; ++mi)
#pragma unroll
        for (int j = 0; j < 4; ++j) {
          const int m = m0 + wr * 64 + mi * 16 + g * 4 + j;
          outf[(size_t)m * DD + n] = acc[mi][ni][j] + bias;
        }
    }
  }
}

// ---------- flash attention v11: padded LDS + BATCHED kvt subtiles ----------
// grid 512 (2 blocks/CU -> grid-limited 2 waves/SIMD; regs are free up to
// 256), block 256 = 4 warps x 32 q-rows, full-seq NT=32, t+2 reg-prefetch.
// Both kvt subtiles batched per tile (R6-verified dataflow): 8 ds_reads ->
// 8 QK MFMAs -> 8 V-frag reads -> 32 exp2/16 cvtpk/8 permlane -> 8 PV MFMAs.
// Doubles independent work per phase so 2 resident waves overlap VALU/MFMA.
__global__ __launch_bounds__(256, 2) void attn8(
    const unsigned short* __restrict__ Qw, const unsigned short* __restrict__ Kw,
    const unsigned short* __restrict__ Vtw, unsigned short* __restrict__ attnw) {
  __shared__ __attribute__((aligned(16))) unsigned short KT[2][64][72];
  __shared__ __attribute__((aligned(16))) unsigned short VT[2][64][72];

  const int f = blockIdx.x;
  const int work = (f & 7) * 64 + (f >> 3);   // bijective: 512 = 8*64
  const int bx = work & 15;                   // q-block (S/128)
  const int bh = work >> 4;                   // 0..31
  const int by = bh & 15, bz = bh >> 4;

  const int tid = threadIdx.x;
  const int lane = tid & 63, wid = tid >> 6;
  const int q = lane & 31, hi = lane >> 5;
  const unsigned short* Qb = Qw + (size_t)bh * SS * HDIM;
  const unsigned short* Kb = Kw + (size_t)bh * SS * HDIM;
  const unsigned short* Vb = Vtw + (size_t)bh * HDIM * SS;
  const int q0 = bx * 128 + wid * 32;

  bh8 qf[4];
#pragma unroll
  for (int ks = 0; ks < 4; ++ks)
    qf[ks] = *(const bh8*)(Qb + (size_t)(q0 + q) * HDIM + ks * 16 + hi * 8);

  f32x16 O0, O1;
#pragma unroll
  for (int r = 0; r < 16; ++r) { O0[r] = 0.f; O1[r] = 0.f; }
  float la[4] = {0.f, 0.f, 0.f, 0.f};

  const int srow = tid >> 2;
  const int scol = (tid & 3) * 16;
  const unsigned short* Ksrc = Kb + (size_t)srow * HDIM + scol;
  const unsigned short* Vsrc = Vb + (size_t)srow * SS + scol;

  bh8 kr0 = *(const bh8*)(Ksrc + 0), kr1 = *(const bh8*)(Ksrc + 8);
  bh8 vr0 = *(const bh8*)(Vsrc + 0), vr1 = *(const bh8*)(Vsrc + 8);
  *(bh8*)&KT[0][srow][scol] = kr0; *(bh8*)&KT[0][srow][scol + 8] = kr1;
  *(bh8*)&VT[0][srow][scol] = vr0; *(bh8*)&VT[0][srow][scol + 8] = vr1;
  kr0 = *(const bh8*)(Ksrc + 64 * HDIM); kr1 = *(const bh8*)(Ksrc + 64 * HDIM + 8);
  vr0 = *(const bh8*)(Vsrc + 64);        vr1 = *(const bh8*)(Vsrc + 64 + 8);

  const int NT = SS / 64;   // 32 tiles, full sequence
  for (int kt = 0; kt < NT; ++kt) {
    const int cur = kt & 1;
    __syncthreads();   // tile kt visible; reads of buf cur^1 (tile kt-1) done
    if (kt + 1 < NT) { // write tile kt+1 into other buffer; prefetch kt+2
      *(bh8*)&KT[cur ^ 1][srow][scol] = kr0;
      *(bh8*)&KT[cur ^ 1][srow][scol + 8] = kr1;
      *(bh8*)&VT[cur ^ 1][srow][scol] = vr0;
      *(bh8*)&VT[cur ^ 1][srow][scol + 8] = vr1;
      if (kt + 2 < NT) {
        const size_t ko = (size_t)(kt + 2) * 64 * HDIM, vo = (size_t)(kt + 2) * 64;
        kr0 = *(const bh8*)(Ksrc + ko); kr1 = *(const bh8*)(Ksrc + ko + 8);
        vr0 = *(const bh8*)(Vsrc + vo); vr1 = *(const bh8*)(Vsrc + vo + 8);
      }
    }

    // ---- K fragments for BOTH kvt subtiles (8 ds_read_b128) ----
    bh8 kf0[4], kf1[4];
#pragma unroll
    for (int ks = 0; ks < 4; ++ks) {
      kf0[ks] = *(const bh8*)&KT[cur][q][ks * 16 + hi * 8];
      kf1[ks] = *(const bh8*)&KT[cur][32 + q][ks * 16 + hi * 8];
    }

    // ---- QK^T both subtiles (8 MFMAs) ----
    f32x16 a0, a1;
#pragma unroll
    for (int r = 0; r < 16; ++r) { a0[r] = 0.f; a1[r] = 0.f; }
    __builtin_amdgcn_s_setprio(1);
#pragma unroll
    for (int ks = 0; ks < 4; ++ks) a0 = MFMA32(kf0[ks], qf[ks], a0);
#pragma unroll
    for (int ks = 0; ks < 4; ++ks) a1 = MFMA32(kf1[ks], qf[ks], a1);
    __builtin_amdgcn_s_setprio(0);

    // ---- V^T fragments, all 8 (issued early; land under softmax) ----
    bh8 vf[2][2][2];   // [kvt][sl][dblk]
#pragma unroll
    for (int kvt = 0; kvt < 2; ++kvt)
#pragma unroll
      for (int sl = 0; sl < 2; ++sl) {
        vf[kvt][sl][0] = *(const bh8*)&VT[cur][q][kvt * 32 + sl * 16 + hi * 8];
        vf[kvt][sl][1] = *(const bh8*)&VT[cur][32 + q][kvt * 32 + sl * 16 + hi * 8];
      }

    // ---- no-max softmax (log2 domain) both subtiles, eager pack ----
    u32 w0[8], w1[8];
#pragma unroll
    for (int i = 0; i < 8; ++i) {
      float p00 = __builtin_amdgcn_exp2f(a0[2 * i]);
      float p01 = __builtin_amdgcn_exp2f(a0[2 * i + 1]);
      la[i & 3] += p00 + p01;
      w0[i] = cvtpk(p00, p01);
    }
#pragma unroll
    for (int i = 0; i < 8; ++i) {
      float p10 = __builtin_amdgcn_exp2f(a1[2 * i]);
      float p11 = __builtin_amdgcn_exp2f(a1[2 * i + 1]);
      la[i & 3] += p10 + p11;
      w1[i] = cvtpk(p10, p11);
    }
    PLSWAP(w0[0], w0[2]); PLSWAP(w0[1], w0[3]);
    PLSWAP(w0[4], w0[6]); PLSWAP(w0[5], w0[7]);
    PLSWAP(w1[0], w1[2]); PLSWAP(w1[1], w1[3]);
    PLSWAP(w1[4], w1[6]); PLSWAP(w1[5], w1[7]);

    // ---- PV: 8 MFMAs (R6-verified interleave) ----
    __builtin_amdgcn_s_setprio(1);
#pragma unroll
    for (int sl = 0; sl < 2; ++sl) {
      union { u32 uw[4]; bh8 h; } pa0, pa1;
#pragma unroll
      for (int j = 0; j < 4; ++j) { pa0.uw[j] = w0[4 * sl + j]; pa1.uw[j] = w1[4 * sl + j]; }
      O0 = MFMA32(vf[0][sl][0], pa0.h, O0);
      O1 = MFMA32(vf[0][sl][1], pa0.h, O1);
      O0 = MFMA32(vf[1][sl][0], pa1.h, O0);
      O1 = MFMA32(vf[1][sl][1], pa1.h, O1);
    }
    __builtin_amdgcn_s_setprio(0);
  }

  // ---- epilogue: l row-total (cross-half once), normalized bf16 output ----
  float l = (la[0] + la[1]) + (la[2] + la[3]);
  {
    float xa = l, xb = l;
    asm("" : "+v"(xb));
    PLSWAP(xa, xb);
    l = xa + xb;
  }
  const float inv = 1.0f / l;
  unsigned short* orow =
      attnw + (size_t)(bz * SS + q0 + q) * DD + by * HDIM;
#pragma unroll
  for (int rq = 0; rq < 4; ++rq) {
    const int db0 = 8 * rq + 4 * hi;
    uint2 v0, v1;
    v0.x = cvtpk(O0[4 * rq + 0] * inv, O0[4 * rq + 1] * inv);
    v0.y = cvtpk(O0[4 * rq + 2] * inv, O0[4 * rq + 3] * inv);
    v1.x = cvtpk(O1[4 * rq + 0] * inv, O1[4 * rq + 1] * inv);
    v1.y = cvtpk(O1[4 * rq + 2] * inv, O1[4 * rq + 3] * inv);
    *(uint2*)(orow + db0) = v0;
    *(uint2*)(orow + 32 + db0) = v1;
  }
}

// ---------- launch ----------
extern "C" void kernel_launch(void* const* d_in, const int* in_sizes, int n_in,
                              void* d_out, int out_size, void* d_ws,
                              size_t ws_size, hipStream_t stream) {
  const float* x  = (const float*)d_in[0];
  const float* Wq = (const float*)d_in[1];
  const float* bq = (const float*)d_in[2];
  const float* Wk = (const float*)d_in[3];
  const float* bk = (const float*)d_in[4];
  const float* Wv = (const float*)d_in[5];
  const float* bv = (const float*)d_in[6];
  const float* Wo = (const float*)d_in[7];
  const float* bo = (const float*)d_in[8];
  float* out = (float*)d_out;

  unsigned short* ws = (unsigned short*)d_ws;
  unsigned short* xb    = ws;                    // 4M  [T,D]
  unsigned short* Wqb   = ws + 4194304;          // 1M x4 (Wq,Wk,Wv,Wo contiguous)
  unsigned short* Qw    = ws + 8388608;          // 4M  [bh][s][hd] (pre-scaled)
  unsigned short* Kw    = ws + 12582912;         // 4M  [bh][s][hd]
  unsigned short* Vtw   = ws + 16777216;         // 4M  [bh][hd][s]
  unsigned short* attnw = ws + 20971520;         // 4M  [T,D]

  cvt_all<<<dim3(4096), 256, 0, stream>>>(x, Wq, Wk, Wv, Wo, xb, Wqb);

  gemm128<0><<<dim3(TT / 128, 3072 / 128), 256, 0, stream>>>(
      xb, Wqb, bq, bk, bv, Qw, Kw, Vtw, nullptr);

  attn8<<<dim3(512), 256, 0, stream>>>(Qw, Kw, Vtw, attnw);

  gemm128<1><<<dim3(TT / 128, DD / 128), 256, 0, stream>>>(
      attnw, Wqb + 3 * 1048576, bo, nullptr, nullptr, nullptr, nullptr, nullptr, out);
}

// Round 22
// 100.569 us; speedup vs baseline: 1.2006x; 1.0104x over previous
//
#include <hip/hip_runtime.h>

// ---------- types ----------
typedef float f32x4  __attribute__((ext_vector_type(4)));
typedef float f32x16 __attribute__((ext_vector_type(16)));
typedef short bh8    __attribute__((ext_vector_type(8)));   // 8 bf16 in 4 VGPRs
typedef unsigned int u32;

#define MFMA16(a, b, c) __builtin_amdgcn_mfma_f32_16x16x32_bf16(a, b, c, 0, 0, 0)
#define MFMA32(a, b, c) __builtin_amdgcn_mfma_f32_32x32x16_bf16(a, b, c, 0, 0, 0)

// dims
#define BB 2
#define SS 2048
#define DD 1024
#define HH 16
#define HDIM 64
#define TT (BB * SS)   // 4096

#define QSCALE 0.18033688011f   // log2(e)/8 : folds 1/sqrt(64) + exp->exp2

__device__ __forceinline__ unsigned short f2bf(float f) {
  unsigned u = __float_as_uint(f);
  u += 0x7fffu + ((u >> 16) & 1u);   // RNE
  return (unsigned short)(u >> 16);
}
__device__ __forceinline__ u32 cvtpk(float lo, float hi) {
  u32 r;
  asm("v_cvt_pk_bf16_f32 %0, %1, %2" : "=v"(r) : "v"(lo), "v"(hi));
  return r;
}
// gfx950 ISA: v_permlane32_swap_b32 vdst, vsrc: a[32:63] <-> b[0:31].
#define PLSWAP(a, b) \
  asm("v_permlane32_swap_b32 %0, %1" : "+v"(a), "+v"(b))

// async global->LDS, 16B per lane (wave-uniform LDS base, lane l -> base+16l)
__device__ __forceinline__ void gload_lds16(const void* gsrc, const void* ldst) {
  __builtin_amdgcn_global_load_lds(
      (const __attribute__((address_space(1))) unsigned int*)(unsigned long long)gsrc,
      (__attribute__((address_space(3))) unsigned int*)(unsigned int)(unsigned long long)ldst,
      16, 0, 0);
}

// ---------- fp32 -> bf16 convert: x + all 4 weights in ONE launch ----------
__global__ void cvt_all(const float* __restrict__ x,
                        const float* __restrict__ w0, const float* __restrict__ w1,
                        const float* __restrict__ w2, const float* __restrict__ w3,
                        unsigned short* __restrict__ xb,
                        unsigned short* __restrict__ wb) {
  const int b = blockIdx.x;
  const float* src;
  unsigned short* dst;
  int i;
  if (b < 2048) {
    src = x; dst = xb;
    i = b * 256 + threadIdx.x;
  } else {
    const int z = (b - 2048) >> 9;             // 0..3
    src = (z == 0) ? w0 : (z == 1) ? w1 : (z == 2) ? w2 : w3;
    dst = wb + (size_t)z * 1048576;
    i = ((b - 2048) & 511) * 256 + threadIdx.x;
  }
  const float4* s = (const float4*)src;
  float4 a = s[i * 2 + 0];
  float4 c = s[i * 2 + 1];
  bh8 v;
  v[0] = (short)f2bf(a.x); v[1] = (short)f2bf(a.y);
  v[2] = (short)f2bf(a.z); v[3] = (short)f2bf(a.w);
  v[4] = (short)f2bf(c.x); v[5] = (short)f2bf(c.y);
  v[6] = (short)f2bf(c.z); v[7] = (short)f2bf(c.w);
  *(bh8*)(dst + (size_t)i * 8) = v;
}

// ---------- QKV GEMM, T3 one-barrier double-buffered pipeline (R20 frozen) ----------
__global__ __launch_bounds__(256, 4) void gemm128(
    const unsigned short* __restrict__ A,
    const unsigned short* __restrict__ Bw,
    const float* __restrict__ b0, const float* __restrict__ b1,
    const float* __restrict__ b2,
    unsigned short* __restrict__ Qw, unsigned short* __restrict__ Kw,
    unsigned short* __restrict__ Vtw) {
  __shared__ __attribute__((aligned(16))) unsigned short As[2][128 * 32];
  __shared__ __attribute__((aligned(16))) unsigned short Bs[2][128 * 32];

  const int tid = threadIdx.x, lane = tid & 63, wid = tid >> 6;
  const int c = lane & 15, g = lane >> 4;
  const int wr = wid >> 1, wc = wid & 1;
  const int m0 = blockIdx.x * 128, n0 = blockIdx.y * 128;

  const unsigned short* Ab = A + (size_t)(m0 + (lane >> 2)) * DD + (lane & 3) * 8;
  const unsigned short* Bb = Bw + (size_t)(n0 + (lane >> 2)) * DD + (lane & 3) * 8;
  const int rowb0 = wid * 32, rowb1 = wid * 32 + 16;   // wave-uniform rows

  f32x4 acc[4][4];
#pragma unroll
  for (int mi = 0; mi < 4; ++mi)
#pragma unroll
    for (int ni = 0; ni < 4; ++ni) acc[mi][ni] = (f32x4){0.f, 0.f, 0.f, 0.f};

  gload_lds16(Ab + (size_t)rowb0 * DD, &As[0][rowb0 * 32]);
  gload_lds16(Ab + (size_t)rowb1 * DD, &As[0][rowb1 * 32]);
  gload_lds16(Bb + (size_t)rowb0 * DD, &Bs[0][rowb0 * 32]);
  gload_lds16(Bb + (size_t)rowb1 * DD, &Bs[0][rowb1 * 32]);
  __syncthreads();   // vmcnt(0) drain: tile 0 visible

  const int NT = DD / 32;   // 32 K-steps
  for (int t = 0; t < NT; ++t) {
    const int cur = t & 1;
    if (t + 1 < NT) {
      const int k1 = (t + 1) * 32;
      gload_lds16(Ab + (size_t)rowb0 * DD + k1, &As[cur ^ 1][rowb0 * 32]);
      gload_lds16(Ab + (size_t)rowb1 * DD + k1, &As[cur ^ 1][rowb1 * 32]);
      gload_lds16(Bb + (size_t)rowb0 * DD + k1, &Bs[cur ^ 1][rowb0 * 32]);
      gload_lds16(Bb + (size_t)rowb1 * DD + k1, &Bs[cur ^ 1][rowb1 * 32]);
    }

    bh8 a[4], b[4];
#pragma unroll
    for (int mi = 0; mi < 4; ++mi)
      a[mi] = *(const bh8*)&As[cur][(wr * 64 + mi * 16 + c) * 32 + g * 8];
#pragma unroll
    for (int ni = 0; ni < 4; ++ni)
      b[ni] = *(const bh8*)&Bs[cur][(wc * 64 + ni * 16 + c) * 32 + g * 8];
    __builtin_amdgcn_s_setprio(1);
#pragma unroll
    for (int mi = 0; mi < 4; ++mi)
#pragma unroll
      for (int ni = 0; ni < 4; ++ni)
        acc[mi][ni] = MFMA16(a[mi], b[ni], acc[mi][ni]);
    __builtin_amdgcn_s_setprio(0);

    __syncthreads();   // retires reads of cur AND publishes tile t+1
  }

#pragma unroll
  for (int ni = 0; ni < 4; ++ni) {
    const int n = n0 + wc * 64 + ni * 16 + c;
    const int z = n >> 10, oo = n & 1023;
    const float bias = (z == 0 ? b0 : (z == 1 ? b1 : b2))[oo];
    const int h = oo >> 6, hd = oo & 63;
    if (z == 2) {
      // V: 4 consecutive s per (mi) -> 2 uint2 stores
#pragma unroll
      for (int mi = 0; mi < 4; ++mi) {
        const int mb = m0 + wr * 64 + mi * 16 + g * 4;
        const int bb = mb >> 11, s = mb & (SS - 1);
        uint2 v;
        v.x = cvtpk(acc[mi][ni][0] + bias, acc[mi][ni][1] + bias);
        v.y = cvtpk(acc[mi][ni][2] + bias, acc[mi][ni][3] + bias);
        *(uint2*)(Vtw + (((size_t)(bb * HH + h) * HDIM + hd) << 11) + s) = v;
      }
    } else {
      unsigned short* O = (z == 0) ? Qw : Kw;
      const float sc = (z == 0) ? QSCALE : 1.0f;
#pragma unroll
      for (int mi = 0; mi < 4; ++mi)
#pragma unroll
        for (int j = 0; j < 4; ++j) {
          const int m = m0 + wr * 64 + mi * 16 + g * 4 + j;
          const int bb = m >> 11, s = m & (SS - 1);
          O[(((size_t)(bb * HH + h) * SS + s) << 6) + hd] =
              f2bf((acc[mi][ni][j] + bias) * sc);
        }
    }
  }
}

// ---------- out-proj GEMM: 64x128 tile for 2 blocks/CU occupancy ----------
// grid (TT/64=64, DD/128=8) = 512 blocks (vs 256 at 128x128 -> 1 blk/CU,
// 1 wave/SIMD, fully-exposed barrier drains). Wave tile 32x64, acc[2][4].
// Same T3 one-barrier pipeline; LDS (64+128)*32*2B*2buf = 24 KB.
__global__ __launch_bounds__(256, 4) void gemm64(
    const unsigned short* __restrict__ A,
    const unsigned short* __restrict__ Bw,
    const float* __restrict__ b0, float* __restrict__ outf) {
  __shared__ __attribute__((aligned(16))) unsigned short As[2][64 * 32];
  __shared__ __attribute__((aligned(16))) unsigned short Bs[2][128 * 32];

  const int tid = threadIdx.x, lane = tid & 63, wid = tid >> 6;
  const int c = lane & 15, g = lane >> 4;
  const int wr = wid >> 1, wc = wid & 1;
  const int m0 = blockIdx.x * 64, n0 = blockIdx.y * 128;

  // A staging: wave w covers rows 16w..16w+15 (1 gload)
  const unsigned short* Ab = A + (size_t)(m0 + (lane >> 2)) * DD + (lane & 3) * 8;
  // B staging: wave w covers rows 32w..32w+31 (2 gloads)
  const unsigned short* Bb = Bw + (size_t)(n0 + (lane >> 2)) * DD + (lane & 3) * 8;
  const int arow = wid * 16;
  const int brow0 = wid * 32, brow1 = wid * 32 + 16;

  f32x4 acc[2][4];
#pragma unroll
  for (int mi = 0; mi < 2; ++mi)
#pragma unroll
    for (int ni = 0; ni < 4; ++ni) acc[mi][ni] = (f32x4){0.f, 0.f, 0.f, 0.f};

  gload_lds16(Ab + (size_t)arow * DD, &As[0][arow * 32]);
  gload_lds16(Bb + (size_t)brow0 * DD, &Bs[0][brow0 * 32]);
  gload_lds16(Bb + (size_t)brow1 * DD, &Bs[0][brow1 * 32]);
  __syncthreads();

  const int NT = DD / 32;
  for (int t = 0; t < NT; ++t) {
    const int cur = t & 1;
    if (t + 1 < NT) {
      const int k1 = (t + 1) * 32;
      gload_lds16(Ab + (size_t)arow * DD + k1, &As[cur ^ 1][arow * 32]);
      gload_lds16(Bb + (size_t)brow0 * DD + k1, &Bs[cur ^ 1][brow0 * 32]);
      gload_lds16(Bb + (size_t)brow1 * DD + k1, &Bs[cur ^ 1][brow1 * 32]);
    }

    bh8 a[2], b[4];
#pragma unroll
    for (int mi = 0; mi < 2; ++mi)
      a[mi] = *(const bh8*)&As[cur][(wr * 32 + mi * 16 + c) * 32 + g * 8];
#pragma unroll
    for (int ni = 0; ni < 4; ++ni)
      b[ni] = *(const bh8*)&Bs[cur][(wc * 64 + ni * 16 + c) * 32 + g * 8];
    __builtin_amdgcn_s_setprio(1);
#pragma unroll
    for (int mi = 0; mi < 2; ++mi)
#pragma unroll
      for (int ni = 0; ni < 4; ++ni)
        acc[mi][ni] = MFMA16(a[mi], b[ni], acc[mi][ni]);
    __builtin_amdgcn_s_setprio(0);

    __syncthreads();
  }

#pragma unroll
  for (int ni = 0; ni < 4; ++ni) {
    const int n = n0 + wc * 64 + ni * 16 + c;
    const float bias = b0[n];
#pragma unroll
    for (int mi = 0; mi < 2; ++mi)
#pragma unroll
      for (int j = 0; j < 4; ++j) {
        const int m = m0 + wr * 32 + mi * 16 + g * 4 + j;
        outf[(size_t)m * DD + n] = acc[mi][ni][j] + bias;
      }
  }
}

// ---------- flash attention v10 (R20 frozen): padded [64][72], seq kvt ----------
__global__ __launch_bounds__(256, 3) void attn8(
    const unsigned short* __restrict__ Qw, const unsigned short* __restrict__ Kw,
    const unsigned short* __restrict__ Vtw, unsigned short* __restrict__ attnw) {
  __shared__ __attribute__((aligned(16))) unsigned short KT[2][64][72];
  __shared__ __attribute__((aligned(16))) unsigned short VT[2][64][72];

  const int f = blockIdx.x;
  const int work = (f & 7) * 64 + (f >> 3);   // bijective: 512 = 8*64
  const int bx = work & 15;                   // q-block (S/128)
  const int bh = work >> 4;                   // 0..31
  const int by = bh & 15, bz = bh >> 4;

  const int tid = threadIdx.x;
  const int lane = tid & 63, wid = tid >> 6;
  const int q = lane & 31, hi = lane >> 5;
  const unsigned short* Qb = Qw + (size_t)bh * SS * HDIM;
  const unsigned short* Kb = Kw + (size_t)bh * SS * HDIM;
  const unsigned short* Vb = Vtw + (size_t)bh * HDIM * SS;
  const int q0 = bx * 128 + wid * 32;

  bh8 qf[4];
#pragma unroll
  for (int ks = 0; ks < 4; ++ks)
    qf[ks] = *(const bh8*)(Qb + (size_t)(q0 + q) * HDIM + ks * 16 + hi * 8);

  f32x16 O0, O1;
#pragma unroll
  for (int r = 0; r < 16; ++r) { O0[r] = 0.f; O1[r] = 0.f; }
  float la[4] = {0.f, 0.f, 0.f, 0.f};

  const int srow = tid >> 2;
  const int scol = (tid & 3) * 16;
  const unsigned short* Ksrc = Kb + (size_t)srow * HDIM + scol;
  const unsigned short* Vsrc = Vb + (size_t)srow * SS + scol;

  bh8 kr0 = *(const bh8*)(Ksrc + 0), kr1 = *(const bh8*)(Ksrc + 8);
  bh8 vr0 = *(const bh8*)(Vsrc + 0), vr1 = *(const bh8*)(Vsrc + 8);
  *(bh8*)&KT[0][srow][scol] = kr0; *(bh8*)&KT[0][srow][scol + 8] = kr1;
  *(bh8*)&VT[0][srow][scol] = vr0; *(bh8*)&VT[0][srow][scol + 8] = vr1;
  kr0 = *(const bh8*)(Ksrc + 64 * HDIM); kr1 = *(const bh8*)(Ksrc + 64 * HDIM + 8);
  vr0 = *(const bh8*)(Vsrc + 64);        vr1 = *(const bh8*)(Vsrc + 64 + 8);

  const int NT = SS / 64;   // 32 tiles, full sequence
  for (int kt = 0; kt < NT; ++kt) {
    const int cur = kt & 1;
    __syncthreads();
    if (kt + 1 < NT) {
      *(bh8*)&KT[cur ^ 1][srow][scol] = kr0;
      *(bh8*)&KT[cur ^ 1][srow][scol + 8] = kr1;
      *(bh8*)&VT[cur ^ 1][srow][scol] = vr0;
      *(bh8*)&VT[cur ^ 1][srow][scol + 8] = vr1;
      if (kt + 2 < NT) {
        const size_t ko = (size_t)(kt + 2) * 64 * HDIM, vo = (size_t)(kt + 2) * 64;
        kr0 = *(const bh8*)(Ksrc + ko); kr1 = *(const bh8*)(Ksrc + ko + 8);
        vr0 = *(const bh8*)(Vsrc + vo); vr1 = *(const bh8*)(Vsrc + vo + 8);
      }
    }

#pragma unroll
    for (int kvt = 0; kvt < 2; ++kvt) {
      bh8 kf[4];
#pragma unroll
      for (int ks = 0; ks < 4; ++ks)
        kf[ks] = *(const bh8*)&KT[cur][kvt * 32 + q][ks * 16 + hi * 8];
      f32x16 a;
#pragma unroll
      for (int r = 0; r < 16; ++r) a[r] = 0.f;
      __builtin_amdgcn_s_setprio(1);
#pragma unroll
      for (int ks = 0; ks < 4; ++ks) a = MFMA32(kf[ks], qf[ks], a);
      __builtin_amdgcn_s_setprio(0);

      bh8 vf00 = *(const bh8*)&VT[cur][q][kvt * 32 + hi * 8];
      bh8 vf01 = *(const bh8*)&VT[cur][32 + q][kvt * 32 + hi * 8];
      bh8 vf10 = *(const bh8*)&VT[cur][q][kvt * 32 + 16 + hi * 8];
      bh8 vf11 = *(const bh8*)&VT[cur][32 + q][kvt * 32 + 16 + hi * 8];

      u32 w[8];
#pragma unroll
      for (int i = 0; i < 8; ++i) {
        float p0 = __builtin_amdgcn_exp2f(a[2 * i]);
        float p1 = __builtin_amdgcn_exp2f(a[2 * i + 1]);
        la[i & 3] += p0 + p1;
        w[i] = cvtpk(p0, p1);
      }
      PLSWAP(w[0], w[2]); PLSWAP(w[1], w[3]);
      PLSWAP(w[4], w[6]); PLSWAP(w[5], w[7]);

      union { u32 uw[4]; bh8 h; } pa0, pa1;
#pragma unroll
      for (int j = 0; j < 4; ++j) { pa0.uw[j] = w[j]; pa1.uw[j] = w[4 + j]; }
      __builtin_amdgcn_s_setprio(1);
      O0 = MFMA32(vf00, pa0.h, O0);
      O1 = MFMA32(vf01, pa0.h, O1);
      O0 = MFMA32(vf10, pa1.h, O0);
      O1 = MFMA32(vf11, pa1.h, O1);
      __builtin_amdgcn_s_setprio(0);
    }
  }

  // ---- epilogue: l row-total (cross-half once), normalized bf16 output ----
  float l = (la[0] + la[1]) + (la[2] + la[3]);
  {
    float xa = l, xb = l;
    asm("" : "+v"(xb));
    PLSWAP(xa, xb);
    l = xa + xb;
  }
  const float inv = 1.0f / l;
  unsigned short* orow =
      attnw + (size_t)(bz * SS + q0 + q) * DD + by * HDIM;
#pragma unroll
  for (int rq = 0; rq < 4; ++rq) {
    const int db0 = 8 * rq + 4 * hi;
    uint2 v0, v1;
    v0.x = cvtpk(O0[4 * rq + 0] * inv, O0[4 * rq + 1] * inv);
    v0.y = cvtpk(O0[4 * rq + 2] * inv, O0[4 * rq + 3] * inv);
    v1.x = cvtpk(O1[4 * rq + 0] * inv, O1[4 * rq + 1] * inv);
    v1.y = cvtpk(O1[4 * rq + 2] * inv, O1[4 * rq + 3] * inv);
    *(uint2*)(orow + db0) = v0;
    *(uint2*)(orow + 32 + db0) = v1;
  }
}

// ---------- launch ----------
extern "C" void kernel_launch(void* const* d_in, const int* in_sizes, int n_in,
                              void* d_out, int out_size, void* d_ws,
                              size_t ws_size, hipStream_t stream) {
  const float* x  = (const float*)d_in[0];
  const float* Wq = (const float*)d_in[1];
  const float* bq = (const float*)d_in[2];
  const float* Wk = (const float*)d_in[3];
  const float* bk = (const float*)d_in[4];
  const float* Wv = (const float*)d_in[5];
  const float* bv = (const float*)d_in[6];
  const float* Wo = (const float*)d_in[7];
  const float* bo = (const float*)d_in[8];
  float* out = (float*)d_out;

  unsigned short* ws = (unsigned short*)d_ws;
  unsigned short* xb    = ws;                    // 4M  [T,D]
  unsigned short* Wqb   = ws + 4194304;          // 1M x4 (Wq,Wk,Wv,Wo contiguous)
  unsigned short* Qw    = ws + 8388608;          // 4M  [bh][s][hd] (pre-scaled)
  unsigned short* Kw    = ws + 12582912;         // 4M  [bh][s][hd]
  unsigned short* Vtw   = ws + 16777216;         // 4M  [bh][hd][s]
  unsigned short* attnw = ws + 20971520;         // 4M  [T,D]

  cvt_all<<<dim3(4096), 256, 0, stream>>>(x, Wq, Wk, Wv, Wo, xb, Wqb);

  gemm128<<<dim3(TT / 128, 3072 / 128), 256, 0, stream>>>(
      xb, Wqb, bq, bk, bv, Qw, Kw, Vtw);

  attn8<<<dim3(512), 256, 0, stream>>>(Qw, Kw, Vtw, attnw);

  gemm64<<<dim3(TT / 64, DD / 128), 256, 0, stream>>>(
      attnw, Wqb + 3 * 1048576, bo, out);
}